// Round 3
// baseline (34644.034 us; speedup 1.0000x reference)
//
#include <hip/hip_runtime.h>
#include <math.h>

#define T_SEQ 2000
#define BATCH 32
#define NSEG  100

typedef unsigned short bf16_t;   // raw bf16 storage

__device__ __forceinline__ float sigmoidf_(float x) {
    return 1.0f / (1.0f + __expf(-x));
}
__device__ __forceinline__ float tanh_(float x) {
    return 1.0f - 2.0f / (__expf(2.0f * x) + 1.0f);
}
__device__ __forceinline__ float bf2f(bf16_t u) {
    return __uint_as_float((unsigned)u << 16);
}
__device__ __forceinline__ bf16_t f2bf(float f) {   // round-to-nearest-even
    unsigned x = __float_as_uint(f);
    return (bf16_t)((x + 0x7FFFu + ((x >> 16) & 1u)) >> 16);
}

// 4 consecutive elements -> float4 (fp32 or bf16 source)
__device__ __forceinline__ float4 ld4(const float* p) { return *(const float4*)p; }
__device__ __forceinline__ float4 ld4(const bf16_t* p) {
    ushort4 u = *(const ushort4*)p;
    return make_float4(bf2f(u.x), bf2f(u.y), bf2f(u.z), bf2f(u.w));
}

// ---------------------------------------------------------------------------
// ws too small -> unmistakable signature instead of a fault
// ---------------------------------------------------------------------------
__global__ void ws_guard_kernel(float* out, int n) {
    int i = blockIdx.x * blockDim.x + threadIdx.x;
    if (i < n) out[i] = 1e30f;
}

// ---------------------------------------------------------------------------
// Generic 3D transpose (fp32): in (D0,D1,D2) -> out (D0,D2,D1)
// ---------------------------------------------------------------------------
__global__ void transpose3(const float* __restrict__ in, float* __restrict__ out,
                           int D0, int D1, int D2) {
    int i = blockIdx.x * blockDim.x + threadIdx.x;
    int tot = D0 * D1 * D2;
    if (i >= tot) return;
    int d0 = i / (D1 * D2);
    int r  = i - d0 * (D1 * D2);
    int d1 = r / D2;
    int d2 = r - d1 * D2;
    out[(size_t)d0 * D1 * D2 + (size_t)d2 * D1 + d1] = in[i];
}

// ---------------------------------------------------------------------------
// Tiled fp32-compute GEMM:  C[m,n] = sum_k A(row(m))[k]*W[n,k] + bias[n]
// MODE 1: conv im2col  A is (B,T,CIN), k = tap*CIN+c, pad=1
// MODE 2: chunk-fwd    m=(bb,r), A row = bb*T_SEQ + (t0+r)
// MODE 3: chunk-bwd    m=(bb,r), A row = bb*T_SEQ + (lens[bb]-1-(t0+r)); t<0 skip
// TA: float | bf16_t (A storage).  OUT_BF: store C as bf16.
// Tile: 256(M) x 64(N) x 32(K); 256 thr; 8x8 micro-tile.
// LDS pitches 258 / 66 keep LDS ops at <=2-way bank aliasing (free, m136).
// ---------------------------------------------------------------------------
template <int MODE, int CIN, typename TA, bool OUT_BF>
__global__ __launch_bounds__(256) void gemm_nt(
    const TA* __restrict__ A, const float* __restrict__ W,
    const float* __restrict__ bias, void* __restrict__ Cout,
    int M, int N, int K, int relu, int t0, int chunkM,
    const int* __restrict__ lens)
{
    __shared__ float As[32 * 258];
    __shared__ float Ws[32 * 66];
    const int tid    = threadIdx.x;
    const int m_base = blockIdx.x * 256;
    const int n_base = blockIdx.y * 64;
    const int m0     = (tid >> 3) * 8;   // 0..248
    const int n0     = (tid & 7) * 8;    // 0..56
    float acc[8][8] = {};

    for (int k0 = 0; k0 < K; k0 += 32) {
        // ---- stage A tile (256 rows x 32 k), 4 elems per thread-iter ----
#pragma unroll
        for (int i = 0; i < 8; ++i) {
            int f4  = i * 256 + tid;
            int row = f4 >> 3;          // 0..255
            int k4  = (f4 & 7) << 2;    // 0..28
            int gm  = m_base + row;
            int gk  = k0 + k4;
            float4 v = make_float4(0.f, 0.f, 0.f, 0.f);
            if (gm < M && gk < K) {
                if constexpr (MODE == 1) {
                    int bb  = gm / T_SEQ;
                    int tt  = gm - bb * T_SEQ;
                    int tap = gk / CIN;
                    int cc  = gk - tap * CIN;
                    int ts  = tt + tap - 1;
                    if (ts >= 0 && ts < T_SEQ)
                        v = ld4(A + ((size_t)(bb * T_SEQ + ts) * CIN + cc));
                } else {
                    int bb = gm / chunkM;
                    int r  = gm - bb * chunkM;
                    int t  = (MODE == 2) ? (t0 + r) : (lens[bb] - 1 - (t0 + r));
                    if (t >= 0 && t < T_SEQ)
                        v = ld4(A + ((size_t)(bb * T_SEQ + t) * K + gk));
                }
            }
            As[(k4 + 0) * 258 + row] = v.x;
            As[(k4 + 1) * 258 + row] = v.y;
            As[(k4 + 2) * 258 + row] = v.z;
            As[(k4 + 3) * 258 + row] = v.w;
        }
        // ---- stage W tile (64 rows x 32 k) ----
#pragma unroll
        for (int i = 0; i < 2; ++i) {
            int f4  = i * 256 + tid;
            int row = f4 >> 3;          // 0..63
            int k4  = (f4 & 7) << 2;
            int gn  = n_base + row;
            int gk  = k0 + k4;
            float4 v = make_float4(0.f, 0.f, 0.f, 0.f);
            if (gk < K)
                v = *(const float4*)(W + (size_t)gn * K + gk);
            Ws[(k4 + 0) * 66 + row] = v.x;
            Ws[(k4 + 1) * 66 + row] = v.y;
            Ws[(k4 + 2) * 66 + row] = v.z;
            Ws[(k4 + 3) * 66 + row] = v.w;
        }
        __syncthreads();
        // ---- inner product ----
#pragma unroll 8
        for (int kk = 0; kk < 32; ++kk) {
            float am[8], wn[8];
#pragma unroll
            for (int j = 0; j < 4; ++j) {
                float2 a = *(const float2*)(As + kk * 258 + m0 + 2 * j);
                am[2 * j] = a.x; am[2 * j + 1] = a.y;
                float2 w = *(const float2*)(Ws + kk * 66 + n0 + 2 * j);
                wn[2 * j] = w.x; wn[2 * j + 1] = w.y;
            }
#pragma unroll
            for (int im = 0; im < 8; ++im)
#pragma unroll
                for (int in = 0; in < 8; ++in)
                    acc[im][in] = fmaf(am[im], wn[in], acc[im][in]);
        }
        __syncthreads();
    }

    // ---- epilogue: bias (+relu) ----
    float bs[8];
#pragma unroll
    for (int j = 0; j < 8; ++j) bs[j] = bias[n_base + n0 + j];
#pragma unroll
    for (int im = 0; im < 8; ++im) {
        int gm = m_base + m0 + im;
        if (gm < M) {
            float o[8];
#pragma unroll
            for (int j = 0; j < 8; ++j) {
                float v = acc[im][j] + bs[j];
                o[j] = relu ? fmaxf(v, 0.f) : v;
            }
            if constexpr (OUT_BF) {
                bf16_t* crow = (bf16_t*)Cout + (size_t)gm * N + n_base + n0;
                ushort4 u0 = { f2bf(o[0]), f2bf(o[1]), f2bf(o[2]), f2bf(o[3]) };
                ushort4 u1 = { f2bf(o[4]), f2bf(o[5]), f2bf(o[6]), f2bf(o[7]) };
                *(ushort4*)(crow)     = u0;
                *(ushort4*)(crow + 4) = u1;
            } else {
                float* crow = (float*)Cout + (size_t)gm * N + n_base + n0;
                *(float4*)(crow)     = make_float4(o[0], o[1], o[2], o[3]);
                *(float4*)(crow + 4) = make_float4(o[4], o[5], o[6], o[7]);
            }
        }
    }
}

// ---------------------------------------------------------------------------
// LSTM recurrence, one phase of `chunk` steps. One block (256 thr) per (b,dir).
// XpF/XpB: (B, chunk, 1024) fp32 projections; bwd rows already time-reversed.
// whhT:    (2, 256, 1024) fp32, gate index contiguous
// state:   (64, 512) fp32 h|c carried across phases
// Hout:    (B, T, 512) bf16; fwd -> [0:256), bwd -> [256:512) at tau
// ---------------------------------------------------------------------------
__global__ __launch_bounds__(256) void lstm_rec_phase(
    const float* __restrict__ XpF, const float* __restrict__ XpB,
    const float* __restrict__ whhT, const int* __restrict__ lens,
    float* __restrict__ state, bf16_t* __restrict__ Hout, int s0, int chunk)
{
    const int bd  = blockIdx.x;
    const int b   = bd >> 1;
    const int d   = bd & 1;
    const int tid = threadIdx.x;
    __shared__ float hs[256];
    __shared__ float gs[1024];
    const int len = lens[b];
    const int s1  = min(s0 + chunk, len);
    float* st = state + bd * 512;
    const float* Wd = whhT + (size_t)d * (256 * 1024);
    const float* Xp = (d ? XpB : XpF) + (size_t)b * ((size_t)chunk * 1024);
    float c;
    if (s0 == 0) { hs[tid] = 0.f; c = 0.f; }
    else         { hs[tid] = st[tid]; c = st[256 + tid]; }
    __syncthreads();
    const int j0 = tid * 4;

    for (int s = s0; s < s1; ++s) {
        const float* xrow = Xp + (size_t)(s - s0) * 1024;
        float4 acc = *(const float4*)(xrow + j0);
#pragma unroll 16
        for (int k = 0; k < 256; ++k) {
            float h  = hs[k];
            float4 w = *(const float4*)(Wd + (size_t)k * 1024 + j0);
            acc.x = fmaf(w.x, h, acc.x);
            acc.y = fmaf(w.y, h, acc.y);
            acc.z = fmaf(w.z, h, acc.z);
            acc.w = fmaf(w.w, h, acc.w);
        }
        *(float4*)(gs + j0) = acc;
        __syncthreads();
        float ig = sigmoidf_(gs[tid]);
        float fg = sigmoidf_(gs[256 + tid]);
        float gg = tanh_(gs[512 + tid]);
        float og = sigmoidf_(gs[768 + tid]);
        c = fmaf(fg, c, ig * gg);
        float hn = og * tanh_(c);
        const int tau = d ? (len - 1 - s) : s;
        Hout[(size_t)(b * T_SEQ + tau) * 512 + (d << 8) + tid] = f2bf(hn);
        __syncthreads();          // all lanes done with hs/gs of this step
        hs[tid] = hn;
        __syncthreads();          // hs stable before next matvec
    }
    st[tid] = hs[tid];
    st[256 + tid] = c;
}

// ---------------------------------------------------------------------------
// Masked mean-pool over time (bf16 in, fp32 atomically accumulated out).
// grid (32, 8), block 256. pooled must be zeroed first.
// ---------------------------------------------------------------------------
__global__ __launch_bounds__(256) void pooled_kernel(
    const bf16_t* __restrict__ L, const int* __restrict__ lens,
    float* __restrict__ pooled)
{
    const int b     = blockIdx.x;
    const int chunk = blockIdx.y;
    const int tid   = threadIdx.x;
    const int len   = lens[b];
    const int t0    = chunk * 250;
    const int t1    = min(t0 + 250, len);
    const float inv = 1.f / fmaxf((float)len, 1.f);
    float s0 = 0.f, s1 = 0.f;
    for (int t = t0; t < t1; ++t) {
        const bf16_t* row = L + (size_t)(b * T_SEQ + t) * 512;
        s0 += bf2f(row[tid]);
        s1 += bf2f(row[tid + 256]);
    }
    if (t1 > t0) {
        atomicAdd(&pooled[b * 512 + tid], s0 * inv);
        atomicAdd(&pooled[b * 512 + 256 + tid], s1 * inv);
    }
}

// ---------------------------------------------------------------------------
// Utterance head: out[b] = relu(pooled@w1.T + b1) @ w2 + b2.  w1T is (512,512)
// transposed so thread u reads w1T[k*512+u] (coalesced). 32 blocks.
// ---------------------------------------------------------------------------
__global__ __launch_bounds__(256) void utt_head(
    const float* __restrict__ pooled,
    const float* __restrict__ w1T, const float* __restrict__ b1,
    const float* __restrict__ w2, const float* __restrict__ b2,
    float* __restrict__ out)
{
    const int b   = blockIdx.x;
    const int tid = threadIdx.x;
    __shared__ float p[512];
    __shared__ float hid[512];
    __shared__ float red[4];
    p[tid]       = pooled[b * 512 + tid];
    p[tid + 256] = pooled[b * 512 + 256 + tid];
    __syncthreads();
#pragma unroll
    for (int half = 0; half < 2; ++half) {
        int u = tid + half * 256;
        float a = b1[u];
#pragma unroll 8
        for (int k = 0; k < 512; ++k) a = fmaf(w1T[(size_t)k * 512 + u], p[k], a);
        hid[u] = fmaxf(a, 0.f);
    }
    __syncthreads();
    float part = hid[tid] * w2[tid] + hid[tid + 256] * w2[tid + 256];
    for (int off = 32; off; off >>= 1) part += __shfl_down(part, off, 64);
    if ((tid & 63) == 0) red[tid >> 6] = part;
    __syncthreads();
    if (tid == 0) out[b] = red[0] + red[1] + red[2] + red[3] + b2[0];
}

// ---------------------------------------------------------------------------
// Fused segment head: mean over [st,en) of bf16 lstm_out -> relu(W1x+b1) -> w2.
// One block per (b,s); w1T transposed for coalesced reads.
// ---------------------------------------------------------------------------
__global__ __launch_bounds__(256) void seg_head(
    const bf16_t* __restrict__ L, const int* __restrict__ lens,
    const int* __restrict__ segs,
    const float* __restrict__ w1T, const float* __restrict__ b1,
    const float* __restrict__ w2, const float* __restrict__ b2,
    const int* __restrict__ seg_lens, float* __restrict__ out)
{
    const int blk = blockIdx.x;
    const int b   = blk / NSEG;
    const int s   = blk - b * NSEG;
    const int tid = threadIdx.x;
    __shared__ float m[512];
    __shared__ float hid[512];
    __shared__ float red[4];
    const int len = lens[b];
    int st = segs[blk * 2 + 0];
    int en = segs[blk * 2 + 1];
    st = min(max(st, 0), len);
    en = max(st + 1, min(en, len));
    const float inv = 1.f / (float)(en - st);
    float a0 = 0.f, a1 = 0.f;
    for (int t = st; t < en; ++t) {
        const bf16_t* row = L + (size_t)(b * T_SEQ + t) * 512;
        a0 += bf2f(row[tid]);
        a1 += bf2f(row[tid + 256]);
    }
    m[tid]       = a0 * inv;
    m[tid + 256] = a1 * inv;
    __syncthreads();
#pragma unroll
    for (int half = 0; half < 2; ++half) {
        int u = tid + half * 256;
        float a = b1[u];
#pragma unroll 8
        for (int k = 0; k < 512; ++k) a = fmaf(w1T[(size_t)k * 512 + u], m[k], a);
        hid[u] = fmaxf(a, 0.f);
    }
    __syncthreads();
    float part = hid[tid] * w2[tid] + hid[tid + 256] * w2[tid + 256];
    for (int off = 32; off; off >>= 1) part += __shfl_down(part, off, 64);
    if ((tid & 63) == 0) red[tid >> 6] = part;
    __syncthreads();
    if (tid == 0)
        out[BATCH + blk] = (s < seg_lens[b]) ? red[0] + red[1] + red[2] + red[3] + b2[0]
                                             : 0.f;
}

// ---------------------------------------------------------------------------
extern "C" void kernel_launch(void* const* d_in, const int* in_sizes, int n_in,
                              void* d_out, int out_size, void* d_ws, size_t ws_size,
                              hipStream_t stream)
{
    const float* features = (const float*)d_in[0];
    const int*   feat_len = (const int*)d_in[1];
    const int*   segs     = (const int*)d_in[2];
    const int*   seg_lens = (const int*)d_in[3];
    const float* conv1_w  = (const float*)d_in[4];
    const float* conv1_b  = (const float*)d_in[5];
    const float* conv2_w  = (const float*)d_in[6];
    const float* conv2_b  = (const float*)d_in[7];
    const float* wih0     = (const float*)d_in[8];
    const float* whh0     = (const float*)d_in[9];
    const float* bias0    = (const float*)d_in[10];
    const float* wih1     = (const float*)d_in[11];
    const float* whh1     = (const float*)d_in[12];
    const float* bias1    = (const float*)d_in[13];
    const float* seg_w1   = (const float*)d_in[14];
    const float* seg_b1   = (const float*)d_in[15];
    const float* seg_w2   = (const float*)d_in[16];
    const float* seg_b2   = (const float*)d_in[17];
    const float* utt_w1   = (const float*)d_in[18];
    const float* utt_b1   = (const float*)d_in[19];
    const float* utt_w2   = (const float*)d_in[20];
    const float* utt_b2   = (const float*)d_in[21];
    float* out = (float*)d_out;
    char*  wsb = (char*)d_ws;

    // ---- byte-granular workspace plan (256B-aligned regions) ----
    size_t off = 0;
    auto alloc = [&](size_t bytes) -> size_t {
        size_t o = off;
        off += (bytes + 255) & ~(size_t)255;
        return o;
    };
    const size_t o_wt1    = alloc(61440  * 4);            // conv1 w (256,240)
    const size_t o_wt2    = alloc(196608 * 4);            // conv2 w (256,768)
    const size_t o_whh0T  = alloc(524288 * 4);            // (2,256,1024)
    const size_t o_whh1T  = alloc(524288 * 4);
    const size_t o_sw1T   = alloc(262144 * 4);            // seg w1 transposed
    const size_t o_uw1T   = alloc(262144 * 4);            // utt w1 transposed
    const size_t o_state  = alloc(32768  * 4);            // (64,512) h|c
    const size_t o_pooled = alloc(16384  * 4);
    const size_t o_Hcat   = alloc((size_t)32768000 * 2);  // bf16 (B,T,512)
    const size_t o_lstm   = alloc((size_t)32768000 * 2);  // bf16 (B,T,512)
    // y1 (bf16 B,T,256) and x2 (bf16 B,T,256) alias inside the lstm region:
    // both are dead before the layer-1 recurrence writes lstm_out.
    const size_t o_y1     = o_lstm;
    const size_t o_x2     = o_lstm + (size_t)16384000 * 2;
    const size_t fixed_end = off;

    // ---- pick the largest chunk whose Xp buffers fit ----
    const int cands[] = {250, 200, 125, 100, 50, 40, 25, 20, 10};
    int chunk = 0;
    size_t o_XpF = 0, o_XpB = 0;
    for (int ci = 0; ci < 9; ++ci) {
        int c = cands[ci];
        size_t xp_bytes = ((size_t)c * 32 * 1024 * 4 + 255) & ~(size_t)255;
        if (fixed_end + 2 * xp_bytes <= ws_size) {
            chunk = c;
            o_XpF = fixed_end;
            o_XpB = fixed_end + xp_bytes;
            break;
        }
    }
    if (chunk == 0) {
        ws_guard_kernel<<<(out_size + 255) / 256, 256, 0, stream>>>(out, out_size);
        return;
    }
    const int nph = T_SEQ / chunk;

    float*  wt1    = (float*)(wsb + o_wt1);
    float*  wt2    = (float*)(wsb + o_wt2);
    float*  whh0T  = (float*)(wsb + o_whh0T);
    float*  whh1T  = (float*)(wsb + o_whh1T);
    float*  sw1T   = (float*)(wsb + o_sw1T);
    float*  uw1T   = (float*)(wsb + o_uw1T);
    float*  state  = (float*)(wsb + o_state);
    float*  pooled = (float*)(wsb + o_pooled);
    bf16_t* Hcat   = (bf16_t*)(wsb + o_Hcat);
    bf16_t* lstm   = (bf16_t*)(wsb + o_lstm);
    bf16_t* y1     = (bf16_t*)(wsb + o_y1);
    bf16_t* x2     = (bf16_t*)(wsb + o_x2);
    float*  XpF    = (float*)(wsb + o_XpF);
    float*  XpB    = (float*)(wsb + o_XpB);

    hipMemsetAsync(state, 0, 32768 * 4, stream);
    hipMemsetAsync(pooled, 0, 16384 * 4, stream);

    // weight re-layouts
    transpose3<<<240, 256, 0, stream>>>(conv1_w, wt1, 256, 80, 3);
    transpose3<<<768, 256, 0, stream>>>(conv2_w, wt2, 256, 256, 3);
    transpose3<<<2048, 256, 0, stream>>>(whh0, whh0T, 2, 1024, 256);
    transpose3<<<2048, 256, 0, stream>>>(whh1, whh1T, 2, 1024, 256);
    transpose3<<<1024, 256, 0, stream>>>(seg_w1, sw1T, 1, 512, 512);
    transpose3<<<1024, 256, 0, stream>>>(utt_w1, uw1T, 1, 512, 512);

    // conv1: (B,T,80) -> bf16 (B,T,256), relu
    gemm_nt<1, 80, float, true><<<dim3(250, 4), 256, 0, stream>>>(
        features, wt1, conv1_b, y1, 64000, 256, 240, 1, 0, 0, feat_len);
    // conv2: bf16 (B,T,256) -> bf16 (B,T,256), relu
    gemm_nt<1, 256, bf16_t, true><<<dim3(250, 4), 256, 0, stream>>>(
        y1, wt2, conv2_b, x2, 64000, 256, 768, 1, 0, 0, feat_len);

    const int gx = (32 * chunk + 255) / 256;

    // ---- layer 0: chunked input projection + recurrence ----
    for (int p = 0; p < nph; ++p) {
        const int t0 = p * chunk;
        gemm_nt<2, 1, bf16_t, false><<<dim3(gx, 16), 256, 0, stream>>>(
            x2, wih0, bias0, XpF, 32 * chunk, 1024, 256, 0, t0, chunk, feat_len);
        gemm_nt<3, 1, bf16_t, false><<<dim3(gx, 16), 256, 0, stream>>>(
            x2, wih0 + 1024 * 256, bias0 + 1024, XpB, 32 * chunk, 1024, 256, 0,
            t0, chunk, feat_len);
        lstm_rec_phase<<<64, 256, 0, stream>>>(
            XpF, XpB, whh0T, feat_len, state, Hcat, t0, chunk);
    }

    // reset recurrent state for layer 1
    hipMemsetAsync(state, 0, 32768 * 4, stream);

    // ---- layer 1: chunked input projection + recurrence ----
    for (int p = 0; p < nph; ++p) {
        const int t0 = p * chunk;
        gemm_nt<2, 1, bf16_t, false><<<dim3(gx, 16), 256, 0, stream>>>(
            Hcat, wih1, bias1, XpF, 32 * chunk, 1024, 512, 0, t0, chunk, feat_len);
        gemm_nt<3, 1, bf16_t, false><<<dim3(gx, 16), 256, 0, stream>>>(
            Hcat, wih1 + 1024 * 512, bias1 + 1024, XpB, 32 * chunk, 1024, 512, 0,
            t0, chunk, feat_len);
        lstm_rec_phase<<<64, 256, 0, stream>>>(
            XpF, XpB, whh1T, feat_len, state, lstm, t0, chunk);  // overwrites y1/x2
    }

    // pooled mean + utterance head
    pooled_kernel<<<dim3(32, 8), 256, 0, stream>>>(lstm, feat_len, pooled);
    utt_head<<<32, 256, 0, stream>>>(pooled, uw1T, utt_b1, utt_w2, utt_b2, out);

    // fused segment means + head
    seg_head<<<3200, 256, 0, stream>>>(lstm, feat_len, segs, sw1T, seg_b1,
                                       seg_w2, seg_b2, seg_lens, out);
}